// Round 6
// baseline (183.860 us; speedup 1.0000x reference)
//
#include <hip/hip_runtime.h>
#include <math.h>

typedef __attribute__((ext_vector_type(8))) unsigned short ushort8;
typedef __attribute__((ext_vector_type(8))) __bf16 bf16x8;
typedef __attribute__((ext_vector_type(4))) float f32x4;

constexpr int   CDIM  = 256;     // channels
constexpr int   HWSP  = 4096;    // H*W
constexpr int   PPB   = 64;      // positions per tile
constexpr float SQRTC = 0.031622776601683794f;  // sqrt(0.001)
constexpr float EPSR  = 1e-6f;

__device__ inline unsigned short f2bf(float x) {  // RNE f32 -> bf16
    unsigned int u = __float_as_uint(x);
    u += 0x7FFFu + ((u >> 16) & 1u);
    return (unsigned short)(u >> 16);
}
// bijective on read (pos=m*16+lr) AND write (pos=4*posq+r) patterns:
// measured SQ_LDS_BANK_CONFLICT == 0 in R4 with this exact function.
__device__ inline int swz(int pos) { return ((pos ^ (pos >> 2)) & 15) << 3; }

// ---- builder: w[256] (circular-conv kernel) -> Wpk in per-lane MFMA B-frag order
// Wpk[ks(8)][tile(16)][lane(64)][j(8)], value = w[(outch-ch)&255],
// outch = tile*16 + (lane&15), ch = ks*32 + (lane>>4)*8 + j.
__global__ void build_wpk(const float* __restrict__ phi,
                          unsigned short* __restrict__ wpk) {
    __shared__ float w[256];
    const int d = threadIdx.x;
    {
        const float step = 6.283185307179586f / 256.0f;
        double s = 0.0;
        for (int k = 1; k <= 127; ++k) {
            int kd = (k * d) & 255;             // exact mod-2pi reduction
            s += 2.0 * (double)cosf(10.0f * phi[k] + step * (float)kd);
        }
        s += (double)cosf(10.0f * phi[0]);
        double c128 = (double)cosf(10.0f * phi[128]);
        s += (d & 1) ? -c128 : c128;
        w[d] = (float)(s * (1.0 / 256.0));      // irfft drops imag at DC/Nyq
    }
    __syncthreads();
    const int l = d & 63, q = d >> 6;
    for (int blk = q; blk < 128; blk += 4) {    // blk = ks*16 + tile
        const int outc = (blk & 15) * 16 + (l & 15);
        const int ch0  = (blk >> 4) * 32 + (l >> 4) * 8;
        ushort8 u;
        #pragma unroll
        for (int j = 0; j < 8; ++j)
            u[j] = f2bf(w[(outc - (ch0 + j)) & 255]);
        *reinterpret_cast<ushort8*>(&wpk[(size_t)(blk * 64 + l) * 8]) = u;
    }
}

// radial Fourier gate: a0 + sum_{n=1..16} a[n-1]cos(rn) + b[n-1]sin(rn)
__device__ inline float fourier_gate(float r, float A0,
                                     const float* __restrict__ a,
                                     const float* __restrict__ b) {
    float sn, cs;
    sincosf(r, &sn, &cs);
    float c = cs, s = sn, f = A0;
    #pragma unroll
    for (int n = 0; n < 16; ++n) {
        f = fmaf(a[n], c, f);
        f = fmaf(b[n], s, f);
        float c2 = fmaf(c, cs, -s * sn);
        float s2 = fmaf(s, cs,  c * sn);
        c = c2; s = s2;
    }
    return f;
}

// Persistent blocks: grid 512 = 256 tile-groups x 2 colors (outch halves).
// W slice lives in 32 VGPR per wave (loaded ONCE) -> no wpk L2 re-reads.
// LDS double-buffer + v[8] reg prefetch keeps HBM loads in flight across
// the MFMA/store phases. waves_per_eu(4,4) prevents R4's 64-reg spill.
__global__ __attribute__((amdgpu_waves_per_eu(4, 4))) __launch_bounds__(512)
void fused_mfma(const float* __restrict__ x,
                const float* __restrict__ a0_1, const float* __restrict__ a1,
                const float* __restrict__ b1,
                const float* __restrict__ a0_2, const float* __restrict__ a2,
                const float* __restrict__ b2,
                const float* __restrict__ phi,
                const float* __restrict__ alpha, const float* __restrict__ beta,
                const unsigned short* __restrict__ wpk,
                float* __restrict__ out, int tpb) {
    __shared__ __align__(16) unsigned short Xl[2][PPB][CDIM];  // 64 KB dbuf
    __shared__ __align__(16) float stats[2][3][8][PPB];        // 12 KB
    __shared__ __align__(16) float sobuf[2][PPB];

    const int t     = threadIdx.x;
    const int l     = t & 63;
    const int w     = t >> 6;                   // wave 0..7
    const int lr    = l & 15;
    const int lk    = l >> 4;
    const int posq  = t & 15;                   // position quad
    const int co    = (t >> 4) & 31;            // channel octet 0..31
    const int g     = blockIdx.x & 255;         // tile group
    const int color = blockIdx.x >> 8;          // outch half
    const int T     = color * 8 + w;            // outch tile (16 ch) this wave owns
    const float bb  = beta[0];

    // ---- W fragments: resident in 32 VGPR for the whole block lifetime ----
    bf16x8 wf[8];
    #pragma unroll
    for (int ks = 0; ks < 8; ++ks)
        wf[ks] = __builtin_bit_cast(bf16x8,
            *reinterpret_cast<const ushort8*>(&wpk[(size_t)((ks * 16 + T) * 64 + l) * 8]));

    f32x4 v[8];                                 // prefetch regs (32 VGPR)
    auto issue_loads = [&](int tau) {
        const float* xb = x + (size_t)(tau >> 6) * CDIM * HWSP + (tau & 63) * PPB;
        #pragma unroll
        for (int j = 0; j < 8; ++j)
            v[j] = *reinterpret_cast<const f32x4*>(
                       &xb[(size_t)(co * 8 + j) * HWSP + posq * 4]);
    };

    const int tau0 = g * tpb;
    issue_loads(tau0);

    for (int i = 0; i < tpb; ++i) {
        const int tau = tau0 + i;
        const int buf = i & 1;
        const float* xb = x   + (size_t)(tau >> 6) * CDIM * HWSP + (tau & 63) * PPB;
        float*       ob = out + (size_t)(tau >> 6) * CDIM * HWSP + (tau & 63) * PPB;

        // ---- consume v: f32 stats + reg-transpose -> swizzled bf16 LDS ----
        {
            f32x4 vns = {0,0,0,0}, vs0 = {0,0,0,0}, vsa = {0,0,0,0};
            #pragma unroll
            for (int j = 0; j < 8; ++j) {
                vns += v[j] * v[j];
                vs0 += v[j];
                vsa  = (j & 1) ? vsa - v[j] : vsa + v[j];
            }
            #pragma unroll
            for (int r = 0; r < 4; ++r) {       // in-register 8x4 transpose
                ushort8 u;
                #pragma unroll
                for (int j = 0; j < 8; ++j) u[j] = f2bf(v[j][r]);
                const int pos = posq * 4 + r;
                *reinterpret_cast<ushort8*>(&Xl[buf][pos][(co * 8) ^ swz(pos)]) = u;
            }
            #pragma unroll
            for (int r = 0; r < 4; ++r) {       // reduce lanes sharing posq
                float aa = vns[r], ss = vs0[r], mm = vsa[r];
                aa += __shfl_xor(aa, 16, 64); aa += __shfl_xor(aa, 32, 64);
                ss += __shfl_xor(ss, 16, 64); ss += __shfl_xor(ss, 32, 64);
                mm += __shfl_xor(mm, 16, 64); mm += __shfl_xor(mm, 32, 64);
                vns[r] = aa; vs0[r] = ss; vsa[r] = mm;
            }
            if (lk == 0) {
                *reinterpret_cast<f32x4*>(&stats[buf][0][w][posq * 4]) = vns;
                *reinterpret_cast<f32x4*>(&stats[buf][1][w][posq * 4]) = vs0;
                *reinterpret_cast<f32x4*>(&stats[buf][2][w][posq * 4]) = vsa;
            }
        }
        __syncthreads();                        // Xl[buf] + stats[buf] ready

        // ---- prefetch next tile: in flight across scalar+MFMA+store ----
        if (i + 1 < tpb) issue_loads(tau + 1);

        // ---- scalar pass (t<64), concurrent with other waves' MFMA ----
        // Parseval: ||dot||^2 = nsq - [S0^2 sin^2(10 phi0) + Sa^2 sin^2(10 phi128)]/256
        if (t < PPB) {
            float nsq = 0.f, S0 = 0.f, Sa = 0.f;
            #pragma unroll
            for (int q = 0; q < 8; ++q) {
                nsq += stats[buf][0][q][t];
                S0  += stats[buf][1][q][t];
                Sa  += stats[buf][2][q][t];
            }
            float sin0 = sinf(10.0f * phi[0]);
            float sinN = sinf(10.0f * phi[128]);
            float n0  = sqrtf(nsq);
            float rn0 = fmaxf(n0, EPSR);
            float arg = fminf(SQRTC * rn0, 1.0f - 1e-5f);
            float ls  = atanhf(arg) / (SQRTC * rn0);
            float r1  = fmaxf(ls * n0, EPSR);
            float s1  = ls * fourier_gate(r1, a0_1[0], a1, b1);
            float dn2 = fmaxf(nsq - (S0 * S0 * sin0 * sin0 + Sa * Sa * sinN * sinN)
                                     * (1.0f / 256.0f), 0.f);
            float nv  = sqrtf(dn2) * fabsf(s1); // ||v0||
            float r2  = fmaxf(nv, EPSR);
            float f2  = fourier_gate(r2, a0_2[0], a2, b2);
            float rn1 = fmaxf(fabsf(f2) * nv, EPSR);
            float es  = tanhf(SQRTC * rn1) / (SQRTC * rn1);
            sobuf[buf][t] = alpha[0] * es * f2 * s1;   // out = so*dot + bb*h0
        }

        // ---- MFMA: pure LDS + resident W regs (no global on critical path) ----
        f32x4 acc[4];
        #pragma unroll
        for (int m = 0; m < 4; ++m) acc[m] = f32x4{0.f, 0.f, 0.f, 0.f};

        #pragma unroll
        for (int ks = 0; ks < 8; ++ks) {
            const int kb = ks * 32 + lk * 8;
            bf16x8 af[4];
            #pragma unroll
            for (int m = 0; m < 4; ++m) {       // A: X rows (pos), LDS b128
                const int pos = m * 16 + lr;
                af[m] = __builtin_bit_cast(bf16x8,
                    *reinterpret_cast<const ushort8*>(&Xl[buf][pos][kb ^ swz(pos)]));
            }
            #pragma unroll
            for (int m = 0; m < 4; ++m)
                acc[m] = __builtin_amdgcn_mfma_f32_16x16x32_bf16(
                    af[m], wf[ks], acc[m], 0, 0, 0);
        }
        __syncthreads();                        // sobuf ready; Xl[buf] reads done

        // ---- epilogue: reg r = 4 consecutive positions -> dwordx4 stores ----
        const int outc = color * 128 + w * 16 + lr;
        if (bb == 0.f) {                        // uniform branch
            #pragma unroll
            for (int m = 0; m < 4; ++m) {
                const int p0 = m * 16 + lk * 4;
                const f32x4 sob = *reinterpret_cast<const f32x4*>(&sobuf[buf][p0]);
                f32x4 vv = acc[m] * sob;
                *reinterpret_cast<f32x4*>(&ob[(size_t)outc * HWSP + p0]) = vv;
            }
        } else {                                // residual path (x re-read, L2-hot)
            #pragma unroll
            for (int m = 0; m < 4; ++m) {
                const int p0 = m * 16 + lk * 4;
                const f32x4 sob = *reinterpret_cast<const f32x4*>(&sobuf[buf][p0]);
                const f32x4 xv = *reinterpret_cast<const f32x4*>(
                                     &xb[(size_t)outc * HWSP + p0]);
                f32x4 vv = acc[m] * sob + bb * xv;
                *reinterpret_cast<f32x4*>(&ob[(size_t)outc * HWSP + p0]) = vv;
            }
        }
    }
}

extern "C" void kernel_launch(void* const* d_in, const int* in_sizes, int n_in,
                              void* d_out, int out_size, void* d_ws, size_t ws_size,
                              hipStream_t stream) {
    const float* x     = (const float*)d_in[0];
    const float* a0_1  = (const float*)d_in[1];
    const float* a1    = (const float*)d_in[2];
    const float* b1    = (const float*)d_in[3];
    const float* a0_2  = (const float*)d_in[4];
    const float* a2    = (const float*)d_in[5];
    const float* b2    = (const float*)d_in[6];
    const float* phi   = (const float*)d_in[7];
    const float* alpha = (const float*)d_in[8];
    const float* beta  = (const float*)d_in[9];

    unsigned short* wpk = (unsigned short*)d_ws;            // 128 KB

    build_wpk<<<1, 256, 0, stream>>>(phi, wpk);

    const int B      = in_sizes[0] / (CDIM * HWSP);         // 32
    const int ntiles = B * (HWSP / PPB);                    // 2048
    const int tpb    = ntiles / 256;                        // 8 tiles per block
    fused_mfma<<<dim3(512), dim3(512), 0, stream>>>(
        x, a0_1, a1, b1, a0_2, a2, b2, phi, alpha, beta, wpk, (float*)d_out, tpb);
}

// Round 7
// 136.759 us; speedup vs baseline: 1.3444x; 1.3444x over previous
//
#include <hip/hip_runtime.h>
#include <math.h>

typedef __attribute__((ext_vector_type(4))) unsigned short ushort4_t;
typedef __attribute__((ext_vector_type(8))) unsigned short ushort8;
typedef __attribute__((ext_vector_type(8))) __bf16 bf16x8;
typedef __attribute__((ext_vector_type(4))) float f32x4;

constexpr int   CDIM  = 256;     // channels
constexpr int   HWSP  = 4096;    // H*W
constexpr int   PPB   = 64;      // positions per tile
constexpr float SQRTC = 0.031622776601683794f;  // sqrt(0.001)
constexpr float EPSR  = 1e-6f;

__device__ inline unsigned short f2bf(float x) {  // RNE f32 -> bf16
    unsigned int u = __float_as_uint(x);
    u += 0x7FFFu + ((u >> 16) & 1u);
    return (unsigned short)(u >> 16);
}
// bijective on read (pos=m*16+lr) AND write (pos=4*posq+r) patterns:
// measured SQ_LDS_BANK_CONFLICT == 0 in R4 with this exact function.
__device__ inline int swz(int pos) { return ((pos ^ (pos >> 2)) & 15) << 3; }

// ---- builder: w[256] (circular-conv kernel) -> Wpk in per-lane MFMA B-frag order
// Wpk[ks(8)][tile(16)][lane(64)][j(8)], value = w[(outch-ch)&255],
// outch = tile*16 + (lane&15), ch = ks*32 + (lane>>4)*8 + j.
__global__ void build_wpk(const float* __restrict__ phi,
                          unsigned short* __restrict__ wpk) {
    __shared__ float w[256];
    const int d = threadIdx.x;
    {
        const float step = 6.283185307179586f / 256.0f;
        double s = 0.0;
        for (int k = 1; k <= 127; ++k) {
            int kd = (k * d) & 255;             // exact mod-2pi reduction
            s += 2.0 * (double)cosf(10.0f * phi[k] + step * (float)kd);
        }
        s += (double)cosf(10.0f * phi[0]);
        double c128 = (double)cosf(10.0f * phi[128]);
        s += (d & 1) ? -c128 : c128;
        w[d] = (float)(s * (1.0 / 256.0));      // irfft drops imag at DC/Nyq
    }
    __syncthreads();
    const int l = d & 63, q = d >> 6;
    for (int blk = q; blk < 128; blk += 4) {    // blk = ks*16 + tile
        const int outc = (blk & 15) * 16 + (l & 15);
        const int ch0  = (blk >> 4) * 32 + (l >> 4) * 8;
        ushort8 u;
        #pragma unroll
        for (int j = 0; j < 8; ++j)
            u[j] = f2bf(w[(outc - (ch0 + j)) & 255]);
        *reinterpret_cast<ushort8*>(&wpk[(size_t)(blk * 64 + l) * 8]) = u;
    }
}

// radial Fourier gate: a0 + sum_{n=1..16} a[n-1]cos(rn) + b[n-1]sin(rn)
__device__ inline float fourier_gate(float r, float A0,
                                     const float* __restrict__ a,
                                     const float* __restrict__ b) {
    float sn, cs;
    sincosf(r, &sn, &cs);
    float c = cs, s = sn, f = A0;
    #pragma unroll
    for (int n = 0; n < 16; ++n) {
        f = fmaf(a[n], c, f);
        f = fmaf(b[n], s, f);
        float c2 = fmaf(c, cs, -s * sn);
        float s2 = fmaf(s, cs,  c * sn);
        c = c2; s = s2;
    }
    return f;
}

// 512 threads = 8 waves; wave w owns outch [32w, 32w+32) -> block covers ALL
// 256 outch (no color split, x read once). W slice resident in 64 VGPR,
// loaded ONCE per persistent block (grid=512, 4 consecutive tiles each).
// launch_bounds(512,4): 4 waves/EU -> 128-VGPR cap, 2 blocks/CU.
// Audited peak live set ~120 VGPR (stage: wf64+v16+stats12+misc; mfma:
// wf64+acc32+af16+misc) -- no spill expected, verify via FETCH/WRITE.
__global__ __launch_bounds__(512, 4)
void fused_mfma(const float* __restrict__ x,
                const float* __restrict__ a0_1, const float* __restrict__ a1,
                const float* __restrict__ b1,
                const float* __restrict__ a0_2, const float* __restrict__ a2,
                const float* __restrict__ b2,
                const float* __restrict__ phi,
                const float* __restrict__ alpha, const float* __restrict__ beta,
                const unsigned short* __restrict__ wpk,
                float* __restrict__ out, int tpb) {
    __shared__ __align__(16) unsigned short Xl[PPB][CDIM];  // 32 KB, swizzled
    __shared__ __align__(16) float stats[3][8][PPB];        // 6 KB
    __shared__ __align__(16) float sobuf[PPB];

    const int t    = threadIdx.x;
    const int l    = t & 63;
    const int w    = t >> 6;                    // wave 0..7: outch 32-slice
    const int lr   = l & 15;
    const int lk   = l >> 4;
    const int posq = t & 15;                    // position quad 0..15
    const int co   = (t >> 4) & 31;             // channel octet 0..31
    const float bb = beta[0];

    // ---- W fragments: resident in 64 VGPR for the whole block lifetime ----
    bf16x8 wf[8][2];
    #pragma unroll
    for (int ks = 0; ks < 8; ++ks)
        #pragma unroll
        for (int n = 0; n < 2; ++n)
            wf[ks][n] = __builtin_bit_cast(bf16x8,
                *reinterpret_cast<const ushort8*>(
                    &wpk[(size_t)((ks * 16 + w * 2 + n) * 64 + l) * 8]));

    for (int i = 0; i < tpb; ++i) {
        const int tau = blockIdx.x * tpb + i;   // consecutive tiles: DRAM locality
        const float* xb = x   + (size_t)(tau >> 6) * CDIM * HWSP + (tau & 63) * PPB;
        float*       ob = out + (size_t)(tau >> 6) * CDIM * HWSP + (tau & 63) * PPB;

        // ---- stage: two v[4] half-passes (16 transient VGPR), f32 stats,
        //      reg transpose, swizzled bf16 LDS (b64 = subset of R4's b128) ----
        {
            f32x4 vns = {0,0,0,0}, vs0 = {0,0,0,0}, vsa = {0,0,0,0};
            #pragma unroll
            for (int hp = 0; hp < 2; ++hp) {
                f32x4 v[4];
                #pragma unroll
                for (int j = 0; j < 4; ++j)
                    v[j] = *reinterpret_cast<const f32x4*>(
                               &xb[(size_t)(co * 8 + hp * 4 + j) * HWSP + posq * 4]);
                #pragma unroll
                for (int j = 0; j < 4; ++j) {
                    vns += v[j] * v[j];
                    vs0 += v[j];
                    vsa  = ((hp * 4 + j) & 1) ? vsa - v[j] : vsa + v[j];
                }
                #pragma unroll
                for (int r = 0; r < 4; ++r) {   // in-register 4x4 transpose
                    ushort4_t u;
                    #pragma unroll
                    for (int j = 0; j < 4; ++j) u[j] = f2bf(v[j][r]);
                    const int pos = posq * 4 + r;
                    *reinterpret_cast<ushort4_t*>(
                        &Xl[pos][((co * 8) ^ swz(pos)) + hp * 4]) = u;
                }
            }
            #pragma unroll
            for (int r = 0; r < 4; ++r) {       // reduce lanes sharing posq
                float aa = vns[r], ss = vs0[r], mm = vsa[r];
                aa += __shfl_xor(aa, 16, 64); aa += __shfl_xor(aa, 32, 64);
                ss += __shfl_xor(ss, 16, 64); ss += __shfl_xor(ss, 32, 64);
                mm += __shfl_xor(mm, 16, 64); mm += __shfl_xor(mm, 32, 64);
                vns[r] = aa; vs0[r] = ss; vsa[r] = mm;
            }
            if (lk == 0) {
                *reinterpret_cast<f32x4*>(&stats[0][w][posq * 4]) = vns;
                *reinterpret_cast<f32x4*>(&stats[1][w][posq * 4]) = vs0;
                *reinterpret_cast<f32x4*>(&stats[2][w][posq * 4]) = vsa;
            }
        }
        __syncthreads();                        // Xl + stats ready

        // ---- scalar pass (wave 0), concurrent with waves 1-7's MFMA ----
        // Parseval: ||dot||^2 = nsq - [S0^2 sin^2(10 phi0) + Sa^2 sin^2(10 phi128)]/256
        if (t < PPB) {
            float nsq = 0.f, S0 = 0.f, Sa = 0.f;
            #pragma unroll
            for (int q = 0; q < 8; ++q) {
                nsq += stats[0][q][t];
                S0  += stats[1][q][t];
                Sa  += stats[2][q][t];
            }
            float sin0 = sinf(10.0f * phi[0]);
            float sinN = sinf(10.0f * phi[128]);
            float n0  = sqrtf(nsq);
            float rn0 = fmaxf(n0, EPSR);
            float arg = fminf(SQRTC * rn0, 1.0f - 1e-5f);
            float ls  = atanhf(arg) / (SQRTC * rn0);
            float r1  = fmaxf(ls * n0, EPSR);
            float s1  = ls * fourier_gate(r1, a0_1[0], a1, b1);
            float dn2 = fmaxf(nsq - (S0 * S0 * sin0 * sin0 + Sa * Sa * sinN * sinN)
                                     * (1.0f / 256.0f), 0.f);
            float nv  = sqrtf(dn2) * fabsf(s1); // ||v0||
            float r2  = fmaxf(nv, EPSR);
            float f2  = fourier_gate(r2, a0_2[0], a2, b2);
            float rn1 = fmaxf(fabsf(f2) * nv, EPSR);
            float es  = tanhf(SQRTC * rn1) / (SQRTC * rn1);
            sobuf[t]  = alpha[0] * es * f2 * s1;   // out = so*dot + bb*h0
        }

        // ---- MFMA: pure LDS + resident W regs (zero global on critical path) ----
        f32x4 acc[4][2];
        #pragma unroll
        for (int m = 0; m < 4; ++m)
            #pragma unroll
            for (int n = 0; n < 2; ++n)
                acc[m][n] = f32x4{0.f, 0.f, 0.f, 0.f};

        #pragma unroll
        for (int ks = 0; ks < 8; ++ks) {
            const int kb = ks * 32 + lk * 8;
            bf16x8 af[4];
            #pragma unroll
            for (int m = 0; m < 4; ++m) {       // A: X rows (pos), LDS b128
                const int pos = m * 16 + lr;
                af[m] = __builtin_bit_cast(bf16x8,
                    *reinterpret_cast<const ushort8*>(&Xl[pos][kb ^ swz(pos)]));
            }
            #pragma unroll
            for (int m = 0; m < 4; ++m)
                #pragma unroll
                for (int n = 0; n < 2; ++n)
                    acc[m][n] = __builtin_amdgcn_mfma_f32_16x16x32_bf16(
                        af[m], wf[ks][n], acc[m][n], 0, 0, 0);
        }
        __syncthreads();                        // sobuf ready; Xl reads done

        // ---- epilogue: reg r = 4 consecutive positions -> dwordx4 stores ----
        if (bb == 0.f) {                        // uniform branch
            #pragma unroll
            for (int m = 0; m < 4; ++m) {
                const int p0 = m * 16 + lk * 4;
                const f32x4 sob = *reinterpret_cast<const f32x4*>(&sobuf[p0]);
                #pragma unroll
                for (int n = 0; n < 2; ++n) {
                    const int outc = w * 32 + n * 16 + lr;
                    f32x4 vv = acc[m][n] * sob;
                    *reinterpret_cast<f32x4*>(&ob[(size_t)outc * HWSP + p0]) = vv;
                }
            }
        } else {                                // residual path (x re-read, L2-hot)
            #pragma unroll
            for (int m = 0; m < 4; ++m) {
                const int p0 = m * 16 + lk * 4;
                const f32x4 sob = *reinterpret_cast<const f32x4*>(&sobuf[p0]);
                #pragma unroll
                for (int n = 0; n < 2; ++n) {
                    const int outc = w * 32 + n * 16 + lr;
                    const f32x4 xv = *reinterpret_cast<const f32x4*>(
                                         &xb[(size_t)outc * HWSP + p0]);
                    f32x4 vv = acc[m][n] * sob + bb * xv;
                    *reinterpret_cast<f32x4*>(&ob[(size_t)outc * HWSP + p0]) = vv;
                }
            }
        }
        // next stage-write to Xl/stats is gated by this iteration's store
        // completing per-thread + the next iteration's barrier (2 bars/tile)
    }
}

extern "C" void kernel_launch(void* const* d_in, const int* in_sizes, int n_in,
                              void* d_out, int out_size, void* d_ws, size_t ws_size,
                              hipStream_t stream) {
    const float* x     = (const float*)d_in[0];
    const float* a0_1  = (const float*)d_in[1];
    const float* a1    = (const float*)d_in[2];
    const float* b1    = (const float*)d_in[3];
    const float* a0_2  = (const float*)d_in[4];
    const float* a2    = (const float*)d_in[5];
    const float* b2    = (const float*)d_in[6];
    const float* phi   = (const float*)d_in[7];
    const float* alpha = (const float*)d_in[8];
    const float* beta  = (const float*)d_in[9];

    unsigned short* wpk = (unsigned short*)d_ws;            // 128 KB

    build_wpk<<<1, 256, 0, stream>>>(phi, wpk);

    const int B      = in_sizes[0] / (CDIM * HWSP);         // 32
    const int ntiles = B * (HWSP / PPB);                    // 2048
    const int nblk   = 512;                                 // 2 per CU
    const int tpb    = ntiles / nblk;                       // 4 tiles per block
    fused_mfma<<<dim3(nblk), dim3(512), 0, stream>>>(
        x, a0_1, a1, b1, a0_2, a2, b2, phi, alpha, beta, wpk, (float*)d_out, tpb);
}

// Round 8
// 83.973 us; speedup vs baseline: 2.1895x; 1.6286x over previous
//
#include <hip/hip_runtime.h>
#include <math.h>

typedef __attribute__((ext_vector_type(8))) unsigned short ushort8;
typedef __attribute__((ext_vector_type(8))) __bf16 bf16x8;
typedef __attribute__((ext_vector_type(4))) float f32x4;

constexpr int   CDIM  = 256;     // channels
constexpr int   HWSP  = 4096;    // H*W
constexpr int   PPB   = 64;      // positions per tile
constexpr float SQRTC = 0.031622776601683794f;  // sqrt(0.001)
constexpr float EPSR  = 1e-6f;

__device__ inline unsigned short f2bf(float x) {  // RNE f32 -> bf16
    unsigned int u = __float_as_uint(x);
    u += 0x7FFFu + ((u >> 16) & 1u);
    return (unsigned short)(u >> 16);
}
// bijective on read (pos=m*16+lr) AND write (pos=4*posq+r) patterns:
// measured SQ_LDS_BANK_CONFLICT == 0 in R5/R7 with this exact function.
__device__ inline int swz(int pos) { return ((pos ^ (pos >> 2)) & 15) << 3; }

// ---- builder: w[256] (circular-conv kernel) -> Wpk in per-lane MFMA B-frag order
// Wpk[ks(8)][tile(16)][lane(64)][j(8)], value = w[(outch-ch)&255],
// outch = tile*16 + (lane&15), ch = ks*32 + (lane>>4)*8 + j.
__global__ void build_wpk(const float* __restrict__ phi,
                          unsigned short* __restrict__ wpk) {
    __shared__ float w[256];
    const int d = threadIdx.x;
    {
        const float step = 6.283185307179586f / 256.0f;
        double s = 0.0;
        for (int k = 1; k <= 127; ++k) {
            int kd = (k * d) & 255;             // exact mod-2pi reduction
            s += 2.0 * (double)cosf(10.0f * phi[k] + step * (float)kd);
        }
        s += (double)cosf(10.0f * phi[0]);
        double c128 = (double)cosf(10.0f * phi[128]);
        s += (d & 1) ? -c128 : c128;
        w[d] = (float)(s * (1.0 / 256.0));      // irfft drops imag at DC/Nyq
    }
    __syncthreads();
    const int l = d & 63, q = d >> 6;
    for (int blk = q; blk < 128; blk += 4) {    // blk = ks*16 + tile
        const int outc = (blk & 15) * 16 + (l & 15);
        const int ch0  = (blk >> 4) * 32 + (l >> 4) * 8;
        ushort8 u;
        #pragma unroll
        for (int j = 0; j < 8; ++j)
            u[j] = f2bf(w[(outc - (ch0 + j)) & 255]);
        *reinterpret_cast<ushort8*>(&wpk[(size_t)(blk * 64 + l) * 8]) = u;
    }
}

// radial Fourier gate: a0 + sum_{n=1..16} a[n-1]cos(rn) + b[n-1]sin(rn)
__device__ inline float fourier_gate(float r, float A0,
                                     const float* __restrict__ a,
                                     const float* __restrict__ b) {
    float sn, cs;
    sincosf(r, &sn, &cs);
    float c = cs, s = sn, f = A0;
    #pragma unroll
    for (int n = 0; n < 16; ++n) {
        f = fmaf(a[n], c, f);
        f = fmaf(b[n], s, f);
        float c2 = fmaf(c, cs, -s * sn);
        float s2 = fmaf(s, cs,  c * sn);
        c = c2; s = s2;
    }
    return f;
}

__global__ __launch_bounds__(256, 4)
void fused_mfma(const float* __restrict__ x,
                const float* __restrict__ a0_1, const float* __restrict__ a1,
                const float* __restrict__ b1,
                const float* __restrict__ a0_2, const float* __restrict__ a2,
                const float* __restrict__ b2,
                const float* __restrict__ phi,
                const float* __restrict__ alpha, const float* __restrict__ beta,
                const unsigned short* __restrict__ wpk,
                float* __restrict__ out) {
    __shared__ __align__(16) unsigned short Xl[PPB][CDIM];  // 32 KB, swizzled
    __shared__ __align__(16) float stats[3][4][PPB];        // nsq / S0 / S_alt
    __shared__ __align__(16) float sobuf[PPB];

    // ---- convoy-buster: hash-staggered start (0..14k cyc, ~60% of the
    //      24k-cyc per-tile period). Uniform phase lengths otherwise keep
    //      all ~680 resident blocks' load-bursts synchronized chip-wide.
    {
        const unsigned bid = blockIdx.x;
        const int h = (bid ^ (bid >> 3) ^ (bid >> 7)) & 7;
        for (int i = 0; i < h; ++i) __builtin_amdgcn_s_sleep(32);
    }

    const int t  = threadIdx.x;
    const int l  = t & 63;
    const int g  = t >> 6;
    const int lr = l & 15;
    const int lk = l >> 4;
    const int b  = blockIdx.x >> 6;
    const int s0 = (blockIdx.x & 63) * PPB;
    const float* xb = x + (size_t)b * CDIM * HWSP + s0;

    // ---- stage: float4 loads (1KB/wave-instr), reg transpose, b128 LDS writes ----
    // thread = (channel octet co, position quad posq); f32 stats pre-rounding.
    f32x4 vns = {0.f,0.f,0.f,0.f}, vs0 = {0.f,0.f,0.f,0.f}, vsa = {0.f,0.f,0.f,0.f};
    const int posq = t & 15;
    #pragma unroll
    for (int i = 0; i < 2; ++i) {
        const int co = i * 16 + (t >> 4);       // channel octet 0..31
        f32x4 v[8];
        #pragma unroll
        for (int j = 0; j < 8; ++j)
            v[j] = *reinterpret_cast<const f32x4*>(
                       &xb[(size_t)(co * 8 + j) * HWSP + posq * 4]);
        #pragma unroll
        for (int j = 0; j < 8; ++j) {
            vns += v[j] * v[j];
            vs0 += v[j];
            vsa  = (j & 1) ? vsa - v[j] : vsa + v[j];
        }
        #pragma unroll
        for (int r = 0; r < 4; ++r) {           // in-register 8x4 transpose
            ushort8 u;
            #pragma unroll
            for (int j = 0; j < 8; ++j) u[j] = f2bf(v[j][r]);
            const int pos = posq * 4 + r;
            *reinterpret_cast<ushort8*>(&Xl[pos][(co * 8) ^ swz(pos)]) = u;
        }
    }
    // reduce over the 4 lanes sharing posq (l^16, l^32), then lk==0 writes
    #pragma unroll
    for (int r = 0; r < 4; ++r) {
        float aa = vns[r], ss = vs0[r], mm = vsa[r];
        aa += __shfl_xor(aa, 16, 64); aa += __shfl_xor(aa, 32, 64);
        ss += __shfl_xor(ss, 16, 64); ss += __shfl_xor(ss, 32, 64);
        mm += __shfl_xor(mm, 16, 64); mm += __shfl_xor(mm, 32, 64);
        vns[r] = aa; vs0[r] = ss; vsa[r] = mm;
    }
    if (lk == 0) {
        *reinterpret_cast<f32x4*>(&stats[0][g][posq * 4]) = vns;
        *reinterpret_cast<f32x4*>(&stats[1][g][posq * 4]) = vs0;
        *reinterpret_cast<f32x4*>(&stats[2][g][posq * 4]) = vsa;
    }
    __syncthreads();

    // ---- single scalar pass (wave 0), hidden under waves 1-3's MFMA ----
    // Parseval: ||dot||^2 = nsq - [S0^2 sin^2(10*phi0) + Sa^2 sin^2(10*phi128)]/256
    if (t < PPB) {
        float nsq = stats[0][0][t] + stats[0][1][t] + stats[0][2][t] + stats[0][3][t];
        float S0  = stats[1][0][t] + stats[1][1][t] + stats[1][2][t] + stats[1][3][t];
        float Sa  = stats[2][0][t] + stats[2][1][t] + stats[2][2][t] + stats[2][3][t];
        float sin0 = sinf(10.0f * phi[0]);
        float sinN = sinf(10.0f * phi[128]);
        float n0  = sqrtf(nsq);
        float rn0 = fmaxf(n0, EPSR);
        float arg = fminf(SQRTC * rn0, 1.0f - 1e-5f);
        float ls  = atanhf(arg) / (SQRTC * rn0);
        float r1  = fmaxf(ls * n0, EPSR);
        float s1  = ls * fourier_gate(r1, a0_1[0], a1, b1);
        float dn2 = fmaxf(nsq - (S0 * S0 * sin0 * sin0 + Sa * Sa * sinN * sinN)
                                 * (1.0f / 256.0f), 0.f);
        float nv  = sqrtf(dn2) * fabsf(s1);     // ||v0||
        float r2  = fmaxf(nv, EPSR);
        float f2  = fourier_gate(r2, a0_2[0], a2, b2);
        float rn1 = fmaxf(fabsf(f2) * nv, EPSR);
        float es  = tanhf(SQRTC * rn1) / (SQRTC * rn1);
        sobuf[t]  = alpha[0] * es * f2 * s1;    // out = so*dot + beta*h0
    }

    // ---- MFMA: D[pos][outch] = X . Wt  (A = X-tile from LDS, B = W packed) ----
    f32x4 acc[4][4];
    #pragma unroll
    for (int m = 0; m < 4; ++m)
        #pragma unroll
        for (int n = 0; n < 4; ++n)
            acc[m][n] = f32x4{0.f, 0.f, 0.f, 0.f};

    #pragma unroll
    for (int ks = 0; ks < 8; ++ks) {
        const int kb = ks * 32 + lk * 8;
        bf16x8 af[4], bw[4];
        #pragma unroll
        for (int m = 0; m < 4; ++m) {           // A: X rows (pos), LDS b128
            const int pos = m * 16 + lr;
            af[m] = __builtin_bit_cast(bf16x8,
                *reinterpret_cast<const ushort8*>(&Xl[pos][kb ^ swz(pos)]));
        }
        #pragma unroll
        for (int n = 0; n < 4; ++n)             // B: W frags, coalesced L2-hot
            bw[n] = __builtin_bit_cast(bf16x8,
                *reinterpret_cast<const ushort8*>(
                    &wpk[(size_t)((ks * 16 + g * 4 + n) * 64 + l) * 8]));
        #pragma unroll
        for (int m = 0; m < 4; ++m)
            #pragma unroll
            for (int n = 0; n < 4; ++n)
                acc[m][n] = __builtin_amdgcn_mfma_f32_16x16x32_bf16(
                    af[m], bw[n], acc[m][n], 0, 0, 0);
    }
    __syncthreads();                            // sobuf ready

    // ---- epilogue: reg r = 4 consecutive positions -> dwordx4 stores ----
    const float bb = beta[0];
    float* ob = out + (size_t)b * CDIM * HWSP + s0;
    if (bb == 0.f) {                            // uniform branch
        #pragma unroll
        for (int m = 0; m < 4; ++m) {
            const int p0 = m * 16 + lk * 4;
            const f32x4 sob = *reinterpret_cast<const f32x4*>(&sobuf[p0]);
            #pragma unroll
            for (int n = 0; n < 4; ++n) {
                const int outc = (g * 4 + n) * 16 + lr;
                f32x4 vv = acc[m][n] * sob;
                *reinterpret_cast<f32x4*>(&ob[(size_t)outc * HWSP + p0]) = vv;
            }
        }
    } else {                                    // residual path (x re-read, L2-hot)
        #pragma unroll
        for (int m = 0; m < 4; ++m) {
            const int p0 = m * 16 + lk * 4;
            const f32x4 sob = *reinterpret_cast<const f32x4*>(&sobuf[p0]);
            #pragma unroll
            for (int n = 0; n < 4; ++n) {
                const int outc = (g * 4 + n) * 16 + lr;
                const f32x4 xv = *reinterpret_cast<const f32x4*>(
                                     &xb[(size_t)outc * HWSP + p0]);
                f32x4 vv = acc[m][n] * sob + bb * xv;
                *reinterpret_cast<f32x4*>(&ob[(size_t)outc * HWSP + p0]) = vv;
            }
        }
    }
}

extern "C" void kernel_launch(void* const* d_in, const int* in_sizes, int n_in,
                              void* d_out, int out_size, void* d_ws, size_t ws_size,
                              hipStream_t stream) {
    const float* x     = (const float*)d_in[0];
    const float* a0_1  = (const float*)d_in[1];
    const float* a1    = (const float*)d_in[2];
    const float* b1    = (const float*)d_in[3];
    const float* a0_2  = (const float*)d_in[4];
    const float* a2    = (const float*)d_in[5];
    const float* b2    = (const float*)d_in[6];
    const float* phi   = (const float*)d_in[7];
    const float* alpha = (const float*)d_in[8];
    const float* beta  = (const float*)d_in[9];

    unsigned short* wpk = (unsigned short*)d_ws;            // 128 KB

    build_wpk<<<1, 256, 0, stream>>>(phi, wpk);

    const int B = in_sizes[0] / (CDIM * HWSP);              // 32
    fused_mfma<<<dim3(B * (HWSP / PPB)), dim3(256), 0, stream>>>(
        x, a0_1, a1, b1, a0_2, a2, b2, phi, alpha, beta, wpk, (float*)d_out);
}

// Round 9
// 82.189 us; speedup vs baseline: 2.2370x; 1.0217x over previous
//
#include <hip/hip_runtime.h>
#include <math.h>

typedef __attribute__((ext_vector_type(8))) unsigned short ushort8;
typedef __attribute__((ext_vector_type(8))) __bf16 bf16x8;
typedef __attribute__((ext_vector_type(4))) float f32x4;

constexpr int   CDIM  = 256;     // channels
constexpr int   HWSP  = 4096;    // H*W
constexpr int   PPB   = 64;      // positions per tile
constexpr float SQRTC = 0.031622776601683794f;  // sqrt(0.001)
constexpr float EPSR  = 1e-6f;

__device__ inline unsigned short f2bf(float x) {  // RNE f32 -> bf16
    unsigned int u = __float_as_uint(x);
    u += 0x7FFFu + ((u >> 16) & 1u);
    return (unsigned short)(u >> 16);
}
// bijective on read (pos=m*16+lr) AND write (pos=4*posq+r) patterns:
// measured SQ_LDS_BANK_CONFLICT == 0 in R5/R7/R8 with this exact function.
__device__ inline int swz(int pos) { return ((pos ^ (pos >> 2)) & 15) << 3; }

// ---- builder: w[256] (circular-conv kernel) -> Wpk in per-lane MFMA B-frag order
// Wpk[ks(8)][tile(16)][lane(64)][j(8)], value = w[(outch-ch)&255],
// outch = tile*16 + (lane&15), ch = ks*32 + (lane>>4)*8 + j.
__global__ void build_wpk(const float* __restrict__ phi,
                          unsigned short* __restrict__ wpk) {
    __shared__ float w[256];
    const int d = threadIdx.x;
    {
        const float step = 6.283185307179586f / 256.0f;
        double s = 0.0;
        for (int k = 1; k <= 127; ++k) {
            int kd = (k * d) & 255;             // exact mod-2pi reduction
            s += 2.0 * (double)cosf(10.0f * phi[k] + step * (float)kd);
        }
        s += (double)cosf(10.0f * phi[0]);
        double c128 = (double)cosf(10.0f * phi[128]);
        s += (d & 1) ? -c128 : c128;
        w[d] = (float)(s * (1.0 / 256.0));      // irfft drops imag at DC/Nyq
    }
    __syncthreads();
    const int l = d & 63, q = d >> 6;
    for (int blk = q; blk < 128; blk += 4) {    // blk = ks*16 + tile
        const int outc = (blk & 15) * 16 + (l & 15);
        const int ch0  = (blk >> 4) * 32 + (l >> 4) * 8;
        ushort8 u;
        #pragma unroll
        for (int j = 0; j < 8; ++j)
            u[j] = f2bf(w[(outc - (ch0 + j)) & 255]);
        *reinterpret_cast<ushort8*>(&wpk[(size_t)(blk * 64 + l) * 8]) = u;
    }
}

// radial Fourier gate: a0 + sum_{n=1..16} a[n-1]cos(rn) + b[n-1]sin(rn)
__device__ inline float fourier_gate(float r, float A0,
                                     const float* __restrict__ a,
                                     const float* __restrict__ b) {
    float sn, cs;
    sincosf(r, &sn, &cs);
    float c = cs, s = sn, f = A0;
    #pragma unroll
    for (int n = 0; n < 16; ++n) {
        f = fmaf(a[n], c, f);
        f = fmaf(b[n], s, f);
        float c2 = fmaf(c, cs, -s * sn);
        float s2 = fmaf(s, cs,  c * sn);
        c = c2; s = s2;
    }
    return f;
}

__global__ __launch_bounds__(256, 4)
void fused_mfma(const float* __restrict__ x,
                const float* __restrict__ a0_1, const float* __restrict__ a1,
                const float* __restrict__ b1,
                const float* __restrict__ a0_2, const float* __restrict__ a2,
                const float* __restrict__ b2,
                const float* __restrict__ phi,
                const float* __restrict__ alpha, const float* __restrict__ beta,
                const unsigned short* __restrict__ wpk,
                float* __restrict__ out) {
    __shared__ __align__(16) unsigned short Xl[PPB][CDIM];  // 32 KB, swizzled
    __shared__ __align__(16) float stats[3][4][PPB];        // nsq / S0 / S_alt
    __shared__ __align__(16) float sobuf[PPB];

    const int t  = threadIdx.x;
    const int l  = t & 63;
    const int g  = t >> 6;
    const int lr = l & 15;
    const int lk = l >> 4;
    const int b  = blockIdx.x >> 6;
    const int s0 = (blockIdx.x & 63) * PPB;
    const float* xb = x + (size_t)b * CDIM * HWSP + s0;

    // ---- stage: ALL 16 float4 loads issued up front (2x load MLP vs R8).
    //      v[16] = 64 transient VGPR, consumed before MFMA (no cross-MFMA
    //      liveness -> no R4-style spill). f32 stats pre-rounding.
    const int posq = t & 15;
    f32x4 v[16];
    #pragma unroll
    for (int i = 0; i < 2; ++i)
        #pragma unroll
        for (int j = 0; j < 8; ++j)
            v[i * 8 + j] = *reinterpret_cast<const f32x4*>(
                &xb[(size_t)((i * 16 + (t >> 4)) * 8 + j) * HWSP + posq * 4]);

    f32x4 vns = {0.f,0.f,0.f,0.f}, vs0 = {0.f,0.f,0.f,0.f}, vsa = {0.f,0.f,0.f,0.f};
    #pragma unroll
    for (int i = 0; i < 2; ++i) {
        const int co = i * 16 + (t >> 4);       // channel octet 0..31
        #pragma unroll
        for (int j = 0; j < 8; ++j) {
            vns += v[i * 8 + j] * v[i * 8 + j];
            vs0 += v[i * 8 + j];
            vsa  = (j & 1) ? vsa - v[i * 8 + j] : vsa + v[i * 8 + j];
        }
        #pragma unroll
        for (int r = 0; r < 4; ++r) {           // in-register 8x4 transpose
            ushort8 u;
            #pragma unroll
            for (int j = 0; j < 8; ++j) u[j] = f2bf(v[i * 8 + j][r]);
            const int pos = posq * 4 + r;
            *reinterpret_cast<ushort8*>(&Xl[pos][(co * 8) ^ swz(pos)]) = u;
        }
    }
    // reduce over the 4 lanes sharing posq (l^16, l^32), then lk==0 writes
    #pragma unroll
    for (int r = 0; r < 4; ++r) {
        float aa = vns[r], ss = vs0[r], mm = vsa[r];
        aa += __shfl_xor(aa, 16, 64); aa += __shfl_xor(aa, 32, 64);
        ss += __shfl_xor(ss, 16, 64); ss += __shfl_xor(ss, 32, 64);
        mm += __shfl_xor(mm, 16, 64); mm += __shfl_xor(mm, 32, 64);
        vns[r] = aa; vs0[r] = ss; vsa[r] = mm;
    }
    if (lk == 0) {
        *reinterpret_cast<f32x4*>(&stats[0][g][posq * 4]) = vns;
        *reinterpret_cast<f32x4*>(&stats[1][g][posq * 4]) = vs0;
        *reinterpret_cast<f32x4*>(&stats[2][g][posq * 4]) = vsa;
    }
    __syncthreads();

    // ---- single scalar pass (wave 0), hidden under waves 1-3's MFMA ----
    // Parseval: ||dot||^2 = nsq - [S0^2 sin^2(10*phi0) + Sa^2 sin^2(10*phi128)]/256
    if (t < PPB) {
        float nsq = stats[0][0][t] + stats[0][1][t] + stats[0][2][t] + stats[0][3][t];
        float S0  = stats[1][0][t] + stats[1][1][t] + stats[1][2][t] + stats[1][3][t];
        float Sa  = stats[2][0][t] + stats[2][1][t] + stats[2][2][t] + stats[2][3][t];
        float sin0 = sinf(10.0f * phi[0]);
        float sinN = sinf(10.0f * phi[128]);
        float n0  = sqrtf(nsq);
        float rn0 = fmaxf(n0, EPSR);
        float arg = fminf(SQRTC * rn0, 1.0f - 1e-5f);
        float ls  = atanhf(arg) / (SQRTC * rn0);
        float r1  = fmaxf(ls * n0, EPSR);
        float s1  = ls * fourier_gate(r1, a0_1[0], a1, b1);
        float dn2 = fmaxf(nsq - (S0 * S0 * sin0 * sin0 + Sa * Sa * sinN * sinN)
                                 * (1.0f / 256.0f), 0.f);
        float nv  = sqrtf(dn2) * fabsf(s1);     // ||v0||
        float r2  = fmaxf(nv, EPSR);
        float f2  = fourier_gate(r2, a0_2[0], a2, b2);
        float rn1 = fmaxf(fabsf(f2) * nv, EPSR);
        float es  = tanhf(SQRTC * rn1) / (SQRTC * rn1);
        sobuf[t]  = alpha[0] * es * f2 * s1;    // out = so*dot + beta*h0
    }

    // ---- MFMA: D[pos][outch] = X . Wt  (A = X-tile from LDS, B = W packed) ----
    f32x4 acc[4][4];
    #pragma unroll
    for (int m = 0; m < 4; ++m)
        #pragma unroll
        for (int n = 0; n < 4; ++n)
            acc[m][n] = f32x4{0.f, 0.f, 0.f, 0.f};

    #pragma unroll
    for (int ks = 0; ks < 8; ++ks) {
        const int kb = ks * 32 + lk * 8;
        bf16x8 af[4], bw[4];
        #pragma unroll
        for (int m = 0; m < 4; ++m) {           // A: X rows (pos), LDS b128
            const int pos = m * 16 + lr;
            af[m] = __builtin_bit_cast(bf16x8,
                *reinterpret_cast<const ushort8*>(&Xl[pos][kb ^ swz(pos)]));
        }
        #pragma unroll
        for (int n = 0; n < 4; ++n)             // B: W frags, coalesced L2-hot
            bw[n] = __builtin_bit_cast(bf16x8,
                *reinterpret_cast<const ushort8*>(
                    &wpk[(size_t)((ks * 16 + g * 4 + n) * 64 + l) * 8]));
        #pragma unroll
        for (int m = 0; m < 4; ++m)
            #pragma unroll
            for (int n = 0; n < 4; ++n)
                acc[m][n] = __builtin_amdgcn_mfma_f32_16x16x32_bf16(
                    af[m], bw[n], acc[m][n], 0, 0, 0);
    }
    __syncthreads();                            // sobuf ready

    // ---- epilogue: nontemporal dwordx4 stores (bypass L2/L3: keep x
    //      L3-resident across replays; out is never re-read) ----
    const float bb = beta[0];
    float* ob = out + (size_t)b * CDIM * HWSP + s0;
    if (bb == 0.f) {                            // uniform branch
        #pragma unroll
        for (int m = 0; m < 4; ++m) {
            const int p0 = m * 16 + lk * 4;
            const f32x4 sob = *reinterpret_cast<const f32x4*>(&sobuf[p0]);
            #pragma unroll
            for (int n = 0; n < 4; ++n) {
                const int outc = (g * 4 + n) * 16 + lr;
                f32x4 vv = acc[m][n] * sob;
                __builtin_nontemporal_store(
                    vv, reinterpret_cast<f32x4*>(&ob[(size_t)outc * HWSP + p0]));
            }
        }
    } else {                                    // residual path (x re-read, L2-hot)
        #pragma unroll
        for (int m = 0; m < 4; ++m) {
            const int p0 = m * 16 + lk * 4;
            const f32x4 sob = *reinterpret_cast<const f32x4*>(&sobuf[p0]);
            #pragma unroll
            for (int n = 0; n < 4; ++n) {
                const int outc = (g * 4 + n) * 16 + lr;
                const f32x4 xv = *reinterpret_cast<const f32x4*>(
                                     &xb[(size_t)outc * HWSP + p0]);
                f32x4 vv = acc[m][n] * sob + bb * xv;
                __builtin_nontemporal_store(
                    vv, reinterpret_cast<f32x4*>(&ob[(size_t)outc * HWSP + p0]));
            }
        }
    }
}

extern "C" void kernel_launch(void* const* d_in, const int* in_sizes, int n_in,
                              void* d_out, int out_size, void* d_ws, size_t ws_size,
                              hipStream_t stream) {
    const float* x     = (const float*)d_in[0];
    const float* a0_1  = (const float*)d_in[1];
    const float* a1    = (const float*)d_in[2];
    const float* b1    = (const float*)d_in[3];
    const float* a0_2  = (const float*)d_in[4];
    const float* a2    = (const float*)d_in[5];
    const float* b2    = (const float*)d_in[6];
    const float* phi   = (const float*)d_in[7];
    const float* alpha = (const float*)d_in[8];
    const float* beta  = (const float*)d_in[9];

    unsigned short* wpk = (unsigned short*)d_ws;            // 128 KB

    build_wpk<<<1, 256, 0, stream>>>(phi, wpk);

    const int B = in_sizes[0] / (CDIM * HWSP);              // 32
    fused_mfma<<<dim3(B * (HWSP / PPB)), dim3(256), 0, stream>>>(
        x, a0_1, a1, b1, a0_2, a2, b2, phi, alpha, beta, wpk, (float*)d_out);
}